// Round 1
// baseline (273.580 us; speedup 1.0000x reference)
//
#include <hip/hip_runtime.h>
#include <hip/hip_bf16.h>

typedef __bf16 bf16_t;
typedef __bf16 bf16x8 __attribute__((ext_vector_type(8)));
typedef float  f32x4  __attribute__((ext_vector_type(4)));

#define T_LEN 200
#define D_DIM 256
#define NTILE 13          // ceil(200/16)
#define NB    4           // batches per main-kernel block

__device__ __forceinline__ float fast_tanh(float x) {
    // tanh(x) = 1 - 2/(e^{2x}+1); saturates correctly at +-1 for |x| large
    float e = __expf(2.0f * x);
    return 1.0f - 2.0f / (e + 1.0f);
}

// ---------------------------------------------------------------------------
// Kernel 1: qpart[b][d] = sum_{k<256} Q[b][k] * W1[d][k]   (f32, exact)
// Written into d_out (read back by kernel 2 before it overwrites with result).
// ---------------------------------------------------------------------------
__global__ __launch_bounds__(256) void qpart_kernel(
    const float* __restrict__ Q, const float* __restrict__ W1,
    float* __restrict__ Out)
{
    __shared__ float qs[8][256];
    const int tid = threadIdx.x;
    const int b0  = blockIdx.x * 8;
    for (int idx = tid; idx < 8 * 256; idx += 256)
        qs[idx >> 8][idx & 255] = Q[(size_t)(b0 + (idx >> 8)) * 256 + (idx & 255)];
    __syncthreads();
    float acc[8];
    #pragma unroll
    for (int i = 0; i < 8; ++i) acc[i] = 0.f;
    const f32x4* Wv = (const f32x4*)(W1 + (size_t)tid * 512);  // row d=tid, k<256
    #pragma unroll 4
    for (int k4 = 0; k4 < 64; ++k4) {
        f32x4 w = Wv[k4];
        #pragma unroll
        for (int bb = 0; bb < 8; ++bb) {
            f32x4 qv = *(const f32x4*)&qs[bb][k4 * 4];   // broadcast read
            acc[bb] += qv[0]*w[0] + qv[1]*w[1] + qv[2]*w[2] + qv[3]*w[3];
        }
    }
    #pragma unroll
    for (int bb = 0; bb < 8; ++bb)
        Out[(size_t)(b0 + bb) * 256 + tid] = acc[bb];
}

// ---------------------------------------------------------------------------
// Kernel 2: fused  tanh(qpart + ub*W1b^T) -> score -> mask -> online softmax
//           -> PV, single pass over user_behavior.
// 512 threads = 8 waves; wave w owns output cols [32w, 32w+32) (2 MFMA n-tiles).
// W1b b-fragments held in registers for the whole kernel (64 VGPR/lane).
// ub tile (16 x 256) staged in LDS as bf16, XOR-swizzled, double buffered.
// ---------------------------------------------------------------------------
__global__ __launch_bounds__(512) void attn_main_kernel(
    const float* __restrict__ U,     // [B,200,256]
    const int*   __restrict__ Mask,  // [B,200]
    const float* __restrict__ W1,    // [256,512]
    const float* __restrict__ W2,    // [256]
    float* __restrict__ Out)         // [B,256]; holds qpart on entry
{
    __shared__ bf16_t ubt[2][16 * 256];
    __shared__ float score_lds[16];
    __shared__ float p_lds[16];
    __shared__ float f_lds;
    __shared__ float l_lds;

    const int tid  = threadIdx.x;
    const int lane = tid & 63;
    const int wv   = tid >> 6;   // wave 0..7
    const int lr   = lane & 15;  // fragment row/col
    const int lg   = lane >> 4;  // k-group 0..3

    // --- load W1b as B-fragments into registers (once per block) ---
    // B operand layout (16x16x32): lane holds B[k=(lane>>4)*8+j][col=lane&15];
    // W1b stored [d][k] => b[j] = W1b[col][ kk*32 + (lane>>4)*8 + j ]
    bf16x8 bq[2][8];
    float  w2v[2];
    #pragma unroll
    for (int n = 0; n < 2; ++n) {
        const int d = wv * 32 + n * 16 + lr;
        const float* wrow = W1 + (size_t)d * 512 + 256;   // W1b row
        #pragma unroll
        for (int kk = 0; kk < 8; ++kk) {
            const float* s = wrow + kk * 32 + lg * 8;
            f32x4 lo = *(const f32x4*)s;
            f32x4 hi = *(const f32x4*)(s + 4);
            bf16x8 v;
            v[0]=(bf16_t)lo[0]; v[1]=(bf16_t)lo[1]; v[2]=(bf16_t)lo[2]; v[3]=(bf16_t)lo[3];
            v[4]=(bf16_t)hi[0]; v[5]=(bf16_t)hi[1]; v[6]=(bf16_t)hi[2]; v[7]=(bf16_t)hi[3];
            bq[n][kk] = v;
        }
        w2v[n] = W2[d];
    }

    // staging geometry: thread -> (row = tid>>5 in 0..15, 8 cols from (tid&31)*8)
    const int srow = tid >> 5;
    const int scol = (tid & 31) * 8;
    const unsigned swoff = (unsigned)srow * 512
                         + (((unsigned)scol * 2) ^ (((unsigned)srow & 7) << 4));

    char* const base0 = (char*)&ubt[0][0];
    char* const base1 = (char*)&ubt[1][0];

    for (int bb = 0; bb < NB; ++bb) {
        const int b = blockIdx.x * NB + bb;
        const float* Ub = U + (size_t)b * (T_LEN * D_DIM);

        float qp[2];
        #pragma unroll
        for (int n = 0; n < 2; ++n)
            qp[n] = Out[(size_t)b * 256 + wv * 32 + n * 16 + lr];  // qpart from k1

        float out_reg = 0.f;
        float m_run = -__builtin_inff(), l_run = 0.f;
        if (tid < 16) score_lds[tid] = 0.f;

        // stage tile 0 -> buf 0 (t0=0, all rows valid)
        {
            const float* src = Ub + (size_t)srow * 256 + scol;
            f32x4 g0 = *(const f32x4*)src;
            f32x4 g1 = *(const f32x4*)(src + 4);
            bf16x8 v;
            v[0]=(bf16_t)g0[0]; v[1]=(bf16_t)g0[1]; v[2]=(bf16_t)g0[2]; v[3]=(bf16_t)g0[3];
            v[4]=(bf16_t)g1[0]; v[5]=(bf16_t)g1[1]; v[6]=(bf16_t)g1[2]; v[7]=(bf16_t)g1[3];
            *(bf16x8*)(base0 + swoff) = v;
        }
        __syncthreads();

        for (int it = 0; it < NTILE; ++it) {
            char* const bcur = (it & 1) ? base1 : base0;
            char* const bnxt = (it & 1) ? base0 : base1;
            const int t0 = it * 16;

            // issue next-tile global loads early (hide HBM under MFMA)
            f32x4 g0 = {0.f,0.f,0.f,0.f}, g1 = {0.f,0.f,0.f,0.f};
            const bool have_next = (it + 1 < NTILE);
            if (have_next) {
                const int t = t0 + 16 + srow;
                if (t < T_LEN) {
                    const float* src = Ub + (size_t)t * 256 + scol;
                    g0 = *(const f32x4*)src;
                    g1 = *(const f32x4*)(src + 4);
                }
            }

            // MFMA: acc[t mod 16][col] over K=256
            f32x4 acc0 = {0.f,0.f,0.f,0.f}, acc1 = {0.f,0.f,0.f,0.f};
            #pragma unroll
            for (int kk = 0; kk < 8; ++kk) {
                const unsigned kb   = (unsigned)(kk * 64 + lg * 16);
                const unsigned aoff = (unsigned)lr * 512
                                    + (kb ^ (((unsigned)lr & 7) << 4));
                bf16x8 a = *(const bf16x8*)(bcur + aoff);
                acc0 = __builtin_amdgcn_mfma_f32_16x16x32_bf16(a, bq[0][kk], acc0, 0, 0, 0);
                acc1 = __builtin_amdgcn_mfma_f32_16x16x32_bf16(a, bq[1][kk], acc1, 0, 0, 0);
            }

            // h = tanh(qpart + acc); partial score = sum_d h*W2 over this wave's 32 cols
            // C layout: row t = (lane>>4)*4 + r, col = lane&15
            float sp[4];
            #pragma unroll
            for (int r = 0; r < 4; ++r) {
                float h0 = fast_tanh(acc0[r] + qp[0]);
                float h1 = fast_tanh(acc1[r] + qp[1]);
                sp[r] = h0 * w2v[0] + h1 * w2v[1];
            }
            #pragma unroll
            for (int r = 0; r < 4; ++r) {
                sp[r] += __shfl_xor(sp[r], 1);
                sp[r] += __shfl_xor(sp[r], 2);
                sp[r] += __shfl_xor(sp[r], 4);
                sp[r] += __shfl_xor(sp[r], 8);
            }
            if (lr == 0) {
                #pragma unroll
                for (int r = 0; r < 4; ++r)
                    atomicAdd(&score_lds[lg * 4 + r], sp[r]);
            }

            // write staged next tile into the other buffer
            if (have_next) {
                bf16x8 v;
                v[0]=(bf16_t)g0[0]; v[1]=(bf16_t)g0[1]; v[2]=(bf16_t)g0[2]; v[3]=(bf16_t)g0[3];
                v[4]=(bf16_t)g1[0]; v[5]=(bf16_t)g1[1]; v[6]=(bf16_t)g1[2]; v[7]=(bf16_t)g1[3];
                *(bf16x8*)(bnxt + swoff) = v;
            }
            __syncthreads();   // B: scores complete, next tile resident

            // online softmax step on wave 0, lanes 0..15 (t = t0 + lane)
            if (tid < 16) {
                float s = score_lds[tid];
                score_lds[tid] = 0.f;                 // re-zero for next tile
                const int t = t0 + tid;
                float sval = -__builtin_inff();
                if (t < T_LEN)
                    sval = (Mask[(size_t)b * T_LEN + t] != 0) ? 0.f : s;
                float tm = sval;
                tm = fmaxf(tm, __shfl_xor(tm, 1));
                tm = fmaxf(tm, __shfl_xor(tm, 2));
                tm = fmaxf(tm, __shfl_xor(tm, 4));
                tm = fmaxf(tm, __shfl_xor(tm, 8));
                const float m_new = fmaxf(m_run, tm);
                const float f = __expf(m_run - m_new);   // 0 on first tile (m_run=-inf)
                const float p = __expf(sval - m_new);    // 0 for padded t
                float ps = p;
                ps += __shfl_xor(ps, 1);
                ps += __shfl_xor(ps, 2);
                ps += __shfl_xor(ps, 4);
                ps += __shfl_xor(ps, 8);
                l_run = l_run * f + ps;
                m_run = m_new;
                p_lds[tid] = p;
                if (tid == 0) f_lds = f;
            }
            __syncthreads();   // C: p/f published

            // incremental PV: out[d] = out[d]*f + sum_j p[j]*ub_tile[j][d]
            if (tid < 256) {
                out_reg *= f_lds;
                #pragma unroll
                for (int j = 0; j < 16; ++j) {
                    const unsigned off = (unsigned)j * 512
                                       + (((unsigned)tid * 2) ^ (((unsigned)j & 7) << 4));
                    out_reg += p_lds[j] * (float)(*(const bf16_t*)(bcur + off));
                }
            }
            __syncthreads();   // A: PV done before buffers are overwritten
        }

        if (tid == 0) l_lds = l_run;
        __syncthreads();
        if (tid < 256)
            Out[(size_t)b * 256 + tid] = out_reg / l_lds;
        __syncthreads();
    }
}

extern "C" void kernel_launch(void* const* d_in, const int* in_sizes, int n_in,
                              void* d_out, int out_size, void* d_ws, size_t ws_size,
                              hipStream_t stream)
{
    const float* Q  = (const float*)d_in[0];
    const float* U  = (const float*)d_in[1];
    const int*   Mk = (const int*)d_in[2];
    const float* W1 = (const float*)d_in[3];
    const float* W2 = (const float*)d_in[4];
    float* Out = (float*)d_out;
    const int B = in_sizes[0] / D_DIM;   // 2048

    qpart_kernel<<<dim3(B / 8), dim3(256), 0, stream>>>(Q, W1, Out);
    attn_main_kernel<<<dim3(B / NB), dim3(512), 0, stream>>>(U, Mk, W1, W2, Out);
}

// Round 2
// 207.318 us; speedup vs baseline: 1.3196x; 1.3196x over previous
//
#include <hip/hip_runtime.h>
#include <hip/hip_bf16.h>

typedef __bf16 bf16_t;
typedef __bf16 bf16x8 __attribute__((ext_vector_type(8)));
typedef float  f32x4  __attribute__((ext_vector_type(4)));

#define T_LEN 200
#define D_DIM 256
#define NTILE 13          // ceil(200/16)
#define NB    2           // batches per main-kernel block

__device__ __forceinline__ float fast_tanh(float x) {
    float e = __expf(2.0f * x);
    return 1.0f - 2.0f / (e + 1.0f);
}

// ---------------------------------------------------------------------------
// Kernel 1: qpart[b][d] = sum_{k<256} Q[b][k] * W1[d][k]   (f32, exact)
// Written into d_out (read back by kernel 2 before it overwrites with result).
// ---------------------------------------------------------------------------
__global__ __launch_bounds__(256) void qpart_kernel(
    const float* __restrict__ Q, const float* __restrict__ W1,
    float* __restrict__ Out)
{
    __shared__ float qs[8][256];
    const int tid = threadIdx.x;
    const int b0  = blockIdx.x * 8;
    for (int idx = tid; idx < 8 * 256; idx += 256)
        qs[idx >> 8][idx & 255] = Q[(size_t)(b0 + (idx >> 8)) * 256 + (idx & 255)];
    __syncthreads();
    float acc[8];
    #pragma unroll
    for (int i = 0; i < 8; ++i) acc[i] = 0.f;
    const f32x4* Wv = (const f32x4*)(W1 + (size_t)tid * 512);
    #pragma unroll 4
    for (int k4 = 0; k4 < 64; ++k4) {
        f32x4 w = Wv[k4];
        #pragma unroll
        for (int bb = 0; bb < 8; ++bb) {
            f32x4 qv = *(const f32x4*)&qs[bb][k4 * 4];
            acc[bb] += qv[0]*w[0] + qv[1]*w[1] + qv[2]*w[2] + qv[3]*w[3];
        }
    }
    #pragma unroll
    for (int bb = 0; bb < 8; ++bb)
        Out[(size_t)(b0 + bb) * 256 + tid] = acc[bb];
}

// ---------------------------------------------------------------------------
// Kernel 2: fused  tanh(qpart + ub*W1b^T)·W2 -> mask -> NO-MAX softmax -> PV.
// Scores are bounded (|h|<=1 => |s| <= ||W2||_1 ~ 13), so p = exp(s) directly:
// no running max, no rescale, no serial section. One barrier per tile.
// Triple-buffered ub tile: PV (post-barrier) reads buf it%3 while staging
// writes buf (it+1)%3; reuse distance 3 = 2 barriers => race-free.
// ---------------------------------------------------------------------------
__global__ __launch_bounds__(512, 4) void attn_main_kernel(
    const float* __restrict__ U,     // [B,200,256]
    const int*   __restrict__ Mask,  // [B,200]
    const float* __restrict__ W1,    // [256,512]
    const float* __restrict__ W2,    // [256]
    float* __restrict__ Out)         // [B,256]; holds qpart on entry
{
    __shared__ bf16_t ubt[3][16 * 256];        // 24 KB, XOR-swizzled
    __shared__ float score_lds[NTILE][16];     // zeroed once per batch
    __shared__ int   msk_lds[208];             // padded past T=200
    __shared__ float out_lds[4][256];          // j-group partial PV
    __shared__ float l_lds[4];                 // j-group partial denom

    const int tid  = threadIdx.x;
    const int lane = tid & 63;
    const int wv   = tid >> 6;   // wave 0..7
    const int lr   = lane & 15;
    const int lg   = lane >> 4;

    // --- W1b B-fragments in registers (whole kernel): 64 VGPR ---
    bf16x8 bq[2][8];
    float  w2v[2];
    #pragma unroll
    for (int n = 0; n < 2; ++n) {
        const int d = wv * 32 + n * 16 + lr;
        const float* wrow = W1 + (size_t)d * 512 + 256;
        #pragma unroll
        for (int kk = 0; kk < 8; ++kk) {
            const float* s = wrow + kk * 32 + lg * 8;
            f32x4 lo = *(const f32x4*)s;
            f32x4 hi = *(const f32x4*)(s + 4);
            bf16x8 v;
            v[0]=(bf16_t)lo[0]; v[1]=(bf16_t)lo[1]; v[2]=(bf16_t)lo[2]; v[3]=(bf16_t)lo[3];
            v[4]=(bf16_t)hi[0]; v[5]=(bf16_t)hi[1]; v[6]=(bf16_t)hi[2]; v[7]=(bf16_t)hi[3];
            bq[n][kk] = v;
        }
        w2v[n] = W2[d];
    }

    // staging geometry: thread -> (row tid>>5, 8 cols from (tid&31)*8)
    const int srow = tid >> 5;
    const int scol = (tid & 31) * 8;
    const unsigned swoff = (unsigned)srow * 512
                         + (((unsigned)scol * 2) ^ (((unsigned)srow & 7) << 4));
    // PV geometry: thread -> d-pair dp (2 cols), j-group jg (4 t's per tile)
    const int dp = tid & 127;
    const int jg = tid >> 7;

    for (int bb = 0; bb < NB; ++bb) {
        const int b = blockIdx.x * NB + bb;
        const float* Ub = U + (size_t)b * (T_LEN * D_DIM);

        float qp[2];
        #pragma unroll
        for (int n = 0; n < 2; ++n)
            qp[n] = Out[(size_t)b * 256 + wv * 32 + n * 16 + lr];

        for (int idx = tid; idx < NTILE * 16; idx += 512)
            ((float*)score_lds)[idx] = 0.f;
        if (tid < 208)
            msk_lds[tid] = (tid < T_LEN) ? Mask[(size_t)b * T_LEN + tid] : 1;

        float op0 = 0.f, op1 = 0.f, l_part = 0.f;

        // stage tile 0 -> buf 0 (all 16 rows valid)
        {
            const float* src = Ub + (size_t)srow * 256 + scol;
            f32x4 g0 = *(const f32x4*)src;
            f32x4 g1 = *(const f32x4*)(src + 4);
            bf16x8 v;
            v[0]=(bf16_t)g0[0]; v[1]=(bf16_t)g0[1]; v[2]=(bf16_t)g0[2]; v[3]=(bf16_t)g0[3];
            v[4]=(bf16_t)g1[0]; v[5]=(bf16_t)g1[1]; v[6]=(bf16_t)g1[2]; v[7]=(bf16_t)g1[3];
            *(bf16x8*)((char*)&ubt[0][0] + swoff) = v;
        }
        __syncthreads();

        for (int it = 0; it < NTILE; ++it) {
            char* const bcur = (char*)&ubt[it % 3][0];
            char* const bnxt = (char*)&ubt[(it + 1) % 3][0];

            // issue next-tile global loads early (hide HBM under MFMA)
            f32x4 g0 = {0.f,0.f,0.f,0.f}, g1 = {0.f,0.f,0.f,0.f};
            bool stage_w = false;
            if (it + 1 < NTILE) {
                const int t = (it + 1) * 16 + srow;
                if (t < T_LEN) {
                    const float* src = Ub + (size_t)t * 256 + scol;
                    g0 = *(const f32x4*)src;
                    g1 = *(const f32x4*)(src + 4);
                    stage_w = true;
                }
            }

            // MFMA: h-tile rows t0..t0+15, this wave's 32 cols, K=256
            f32x4 acc0 = {0.f,0.f,0.f,0.f}, acc1 = {0.f,0.f,0.f,0.f};
            #pragma unroll
            for (int kk = 0; kk < 8; ++kk) {
                const unsigned kb   = (unsigned)(kk * 64 + lg * 16);
                const unsigned aoff = (unsigned)lr * 512
                                    + (kb ^ (((unsigned)lr & 7) << 4));
                bf16x8 a = *(const bf16x8*)(bcur + aoff);
                acc0 = __builtin_amdgcn_mfma_f32_16x16x32_bf16(a, bq[0][kk], acc0, 0, 0, 0);
                acc1 = __builtin_amdgcn_mfma_f32_16x16x32_bf16(a, bq[1][kk], acc1, 0, 0, 0);
            }

            // write staged next tile (other buffer)
            if (stage_w) {
                bf16x8 v;
                v[0]=(bf16_t)g0[0]; v[1]=(bf16_t)g0[1]; v[2]=(bf16_t)g0[2]; v[3]=(bf16_t)g0[3];
                v[4]=(bf16_t)g1[0]; v[5]=(bf16_t)g1[1]; v[6]=(bf16_t)g1[2]; v[7]=(bf16_t)g1[3];
                *(bf16x8*)(bnxt + swoff) = v;
            }

            // partial scores: sum over this wave's 32 cols; row t0+lg*4+r
            float sp[4];
            #pragma unroll
            for (int r = 0; r < 4; ++r) {
                float h0 = fast_tanh(acc0[r] + qp[0]);
                float h1 = fast_tanh(acc1[r] + qp[1]);
                sp[r] = h0 * w2v[0] + h1 * w2v[1];
            }
            #pragma unroll
            for (int r = 0; r < 4; ++r) {
                sp[r] += __shfl_xor(sp[r], 1);
                sp[r] += __shfl_xor(sp[r], 2);
                sp[r] += __shfl_xor(sp[r], 4);
                sp[r] += __shfl_xor(sp[r], 8);
            }
            if (lr == 0) {
                #pragma unroll
                for (int r = 0; r < 4; ++r)
                    atomicAdd(&score_lds[it][lg * 4 + r], sp[r]);
            }

            __syncthreads();   // scores complete, next tile resident

            // back phase: p = exp(masked s) (no max), l accumulate, PV
            #pragma unroll
            for (int jj = 0; jj < 4; ++jj) {
                const int j = jg * 4 + jj;
                const int t = it * 16 + j;
                const float s = score_lds[it][j];
                float p = 0.f;
                if (t < T_LEN)
                    p = msk_lds[t] ? 1.0f : __expf(s);
                l_part += p;
                const unsigned off = (unsigned)j * 512
                                   + (((unsigned)dp * 4) ^ (((unsigned)j & 7) << 4));
                const unsigned w = *(const unsigned*)(bcur + off);
                const float u0 = __builtin_bit_cast(float, w << 16);
                const float u1 = __builtin_bit_cast(float, w & 0xffff0000u);
                op0 += p * u0;
                op1 += p * u1;
            }
            // no trailing barrier: PV reads of buf it%3 are drained at the
            // next iteration's barrier; staging reuses buf it%3 only at it+3.
        }

        // batch epilogue: combine 4 j-group partials
        out_lds[jg][dp * 2]     = op0;
        out_lds[jg][dp * 2 + 1] = op1;
        if ((tid & 127) == 0) l_lds[jg] = l_part;
        __syncthreads();
        if (tid < 256) {
            const float l = l_lds[0] + l_lds[1] + l_lds[2] + l_lds[3];
            const float o = out_lds[0][tid] + out_lds[1][tid]
                          + out_lds[2][tid] + out_lds[3][tid];
            Out[(size_t)b * 256 + tid] = o / l;
        }
        __syncthreads();   // protect LDS reuse by next batch
    }
}

extern "C" void kernel_launch(void* const* d_in, const int* in_sizes, int n_in,
                              void* d_out, int out_size, void* d_ws, size_t ws_size,
                              hipStream_t stream)
{
    const float* Q  = (const float*)d_in[0];
    const float* U  = (const float*)d_in[1];
    const int*   Mk = (const int*)d_in[2];
    const float* W1 = (const float*)d_in[3];
    const float* W2 = (const float*)d_in[4];
    float* Out = (float*)d_out;
    const int B = in_sizes[0] / D_DIM;   // 2048

    qpart_kernel<<<dim3(B / 8), dim3(256), 0, stream>>>(Q, W1, Out);
    attn_main_kernel<<<dim3(B / NB), dim3(512), 0, stream>>>(U, Mk, W1, W2, Out);
}